// Round 5
// baseline (506.707 us; speedup 1.0000x reference)
//
#include <hip/hip_runtime.h>
#include <math.h>

#ifndef M_PI
#define M_PI 3.14159265358979323846
#endif

// Problem constants (from the reference)
constexpr int    NSAMP  = 2048;
constexpr float  STEPf  = 2048.0f / 2047.0f;       // linspace(-1024,1024,2048) step
constexpr float  DXf    = 6.0e-6f;                 // 3e-6 / 0.5
constexpr float  EPSf   = 2.2204e-16f;
constexpr double Kd     = 2.0 * M_PI / 3.55e-7;    // ~1.7698956e7
constexpr double INV2PI = 1.0 / (2.0 * M_PI);

// Packed fp32 via compiler vectorization: <2 x float> arithmetic selects
// v_pk_{fma,mul,add}_f32 on gfx950 (packed-FP32 target feature). No inline asm.
typedef float f32x2 __attribute__((ext_vector_type(2)));
__device__ __forceinline__ f32x2 splat2(float s) { f32x2 r; r.x = s; r.y = s; return r; }

// ---------------------------------------------------------------------------
// Gather per-(batch,particle) parameters; precompute per-set constants (fp64).
// prm layout per (b,p), stride 16:
//   0:xm 1:ym
//   per set s in {hat,gt} at offset 2+6s:
//     +0: carg   (x = carg*rho; branch predicate)
//     +1: crev   = carg/2pi
//     +2: c8     = 8/carg                 (z = min(c8*invr, 1))
//     +3: csql   = camp*sqrt(0.636619772/carg)  (amp_l = csql*invr^1.5*B)
//     +4: camp   = rs/2
//     +5: cph    = K/(2*zs*2pi)
// ---------------------------------------------------------------------------
__global__ void gather_params_kernel(const float* __restrict__ yh,
                                     const float* __restrict__ ygt,
                                     const int*   __restrict__ xs,
                                     const int*   __restrict__ ys,
                                     float* __restrict__ prm,
                                     double* __restrict__ acc) {
    int t = threadIdx.x;
    if (t == 0) *acc = 0.0;   // zero accumulator every launch (graph replay safe)
    if (t < 8) {
        const int M = 512;
        int b = t >> 2, p = t & 3;
        int ix = xs[b * 4 + p];
        int iy = ys[b * 4 + p];
        float rs_h = 50.0f  * yh [((b * 3 + 2) * M + iy) * M + ix];
        float zs_h = 200.0f * yh [((b * 3 + 1) * M + iy) * M + ix];
        float rs_g =          ygt[((b * 5 + 2) * M + iy) * M + ix];
        float zs_g =          ygt[((b * 5 + 1) * M + iy) * M + ix];
        double rph = (double)rs_h * 1e-6, zph = (double)zs_h * 1e-3;
        double rpg = (double)rs_g * 1e-6, zpg = (double)zs_g * 1e-3;

        float* o = prm + t * 16;
        o[0] = ((float)(ix * 4) - 1024.0f) * DXf;
        o[1] = ((float)(iy * 4) - 1024.0f) * DXf;

        double carg_h = Kd * rph / zph;
        o[2] = (float)carg_h;
        o[3] = (float)(carg_h * INV2PI);
        o[4] = (float)(8.0 / carg_h);
        o[5] = (float)(0.5 * rph * sqrt(0.636619772 / carg_h));
        o[6] = (float)(0.5 * rph);
        o[7] = (float)(Kd / (2.0 * zph) * INV2PI);

        double carg_g = Kd * rpg / zpg;
        o[8]  = (float)carg_g;
        o[9]  = (float)(carg_g * INV2PI);
        o[10] = (float)(8.0 / carg_g);
        o[11] = (float)(0.5 * rpg * sqrt(0.636619772 / carg_g));
        o[12] = (float)(0.5 * rpg);
        o[13] = (float)(Kd / (2.0 * zpg) * INV2PI);
        o[14] = 0.0f; o[15] = 0.0f;
    }
}

// One particle-set contribution for a pair of points. All values finite on all
// lanes (both branch inputs clamped, round-2-proven), select per component.
__device__ __forceinline__ void accum_set2(const float* __restrict__ c,
                                           f32x2 rho, f32x2 invr, f32x2 r2,
                                           f32x2 ivs /* invr^1.5 */,
                                           f32x2& S, f32x2& C) {
    const f32x2 x = splat2(c[0]) * rho;
    // --- small branch: NR rational on clamped xc = min(x,8) ---
    f32x2 xc; xc.x = fminf(x.x, 8.0f); xc.y = fminf(x.y, 8.0f);
    f32x2 yy = xc * xc;
    f32x2 nt = yy * splat2(-30.16036606f) + splat2(15704.48260f);
    nt = yy * nt + splat2(-2972611.439f);
    nt = yy * nt + splat2(242396853.1f);
    nt = yy * nt + splat2(-7895059235.0f);
    nt = yy * nt + splat2(72362614232.0f);
    f32x2 num = nt * xc;
    f32x2 dt = yy + splat2(376.9991397f);
    dt = yy * dt + splat2(99447.43394f);
    dt = yy * dt + splat2(18583304.74f);
    dt = yy * dt + splat2(2300535178.0f);
    dt = yy * dt + splat2(144725228442.0f);
    f32x2 rc; rc.x = __builtin_amdgcn_rcpf(dt.x); rc.y = __builtin_amdgcn_rcpf(dt.y);
    f32x2 a_s = (splat2(c[4]) * invr) * (num * rc);
    // --- large branch: truncated asymptotic, z = min(8/x, 1) ---
    f32x2 z; z.x = fminf(c[2] * invr.x, 1.0f); z.y = fminf(c[2] * invr.y, 1.0f);
    f32x2 y2 = z * z;
    f32x2 rev = splat2(c[1]) * rho + splat2(-0.375f);   // (x - 3pi/4)/2pi
    f32x2 f1; f1.x = __builtin_amdgcn_fractf(rev.x); f1.y = __builtin_amdgcn_fractf(rev.y);
    f32x2 s1, c1;
    s1.x = __builtin_amdgcn_sinf(f1.x); s1.y = __builtin_amdgcn_sinf(f1.y);
    c1.x = __builtin_amdgcn_cosf(f1.x); c1.y = __builtin_amdgcn_cosf(f1.y);
    f32x2 p1 = y2 * splat2(0.183105e-2f) + splat2(1.0f);
    f32x2 p2 = y2 * splat2(-0.2002690873e-3f) + splat2(0.04687499995f);
    f32x2 B  = c1 * p1 - (z * s1) * p2;
    f32x2 a_l = (splat2(c[3]) * ivs) * B;
    // --- select on x<8, per component ---
    f32x2 amp;
    amp.x = (x.x < 8.0f) ? a_s.x : a_l.x;
    amp.y = (x.y < 8.0f) ? a_s.y : a_l.y;
    // --- phase: rev = cph*r2, scalar-FMA residual restores low bits ---
    float cph = c[5];
    f32x2 hi = splat2(cph) * r2;
    f32x2 fr;
    fr.x = __builtin_amdgcn_fractf(hi.x) + fmaf(cph, r2.x, -hi.x);
    fr.y = __builtin_amdgcn_fractf(hi.y) + fmaf(cph, r2.y, -hi.y);
    f32x2 sn, cs;
    sn.x = __builtin_amdgcn_sinf(fr.x); sn.y = __builtin_amdgcn_sinf(fr.y);
    cs.x = __builtin_amdgcn_cosf(fr.x); cs.y = __builtin_amdgcn_cosf(fr.y);
    S = amp * sn + S;
    C = amp * cs + C;
}

// 8192 blocks x 256 threads; 4 points/thread (2 point-pairs), uniform batch.
__global__ __launch_bounds__(256, 3) void holo_mse_kernel(
        const float* __restrict__ prm, double* __restrict__ acc) {
    __shared__ float sp[128];
    __shared__ float wsum[4];
    if (threadIdx.x < 128) sp[threadIdx.x] = prm[threadIdx.x];
    __syncthreads();

    int blk = blockIdx.x;
    int b   = blk >> 12;                            // block-uniform batch
    int r   = ((blk & 4095) << 8) + threadIdx.x;    // [0, 2^20)
    int i0  = r >> 11;                              // row base (0..511)
    int j   = r & (NSAMP - 1);

    float nj = fmaf((float)j, STEPf, -1024.0f) * DXf;
    f32x2 ni[2];
    ni[0].x = fmaf((float)(i0       ), STEPf, -1024.0f) * DXf;
    ni[0].y = fmaf((float)(i0 +  512), STEPf, -1024.0f) * DXf;
    ni[1].x = fmaf((float)(i0 + 1024), STEPf, -1024.0f) * DXf;
    ni[1].y = fmaf((float)(i0 + 1536), STEPf, -1024.0f) * DXf;

    f32x2 Sh[2], Ch[2], Sg[2], Cg[2];
    #pragma unroll
    for (int kk = 0; kk < 2; ++kk) {
        Sh[kk] = splat2(0.0f); Ch[kk] = splat2(0.0f);
        Sg[kk] = splat2(0.0f); Cg[kk] = splat2(0.0f);
    }

    #pragma unroll
    for (int p = 0; p < 4; ++p) {
        const float* q = &sp[(b * 4 + p) * 16];
        float xm = q[0], ym = q[1];
        float dxs = (nj - xm) + EPSf;        // EPS after subtract (ref semantics)
        f32x2 dx2 = splat2(dxs * dxs);

        #pragma unroll
        for (int kk = 0; kk < 2; ++kk) {
            f32x2 dy = (ni[kk] - splat2(ym)) + splat2(EPSf);
            f32x2 r2 = dy * dy + dx2;
            f32x2 invr, rho, ivs;
            invr.x = __builtin_amdgcn_rsqf(r2.x);
            invr.y = __builtin_amdgcn_rsqf(r2.y);
            rho = r2 * invr;
            f32x2 sv;
            sv.x = __builtin_amdgcn_sqrtf(invr.x);
            sv.y = __builtin_amdgcn_sqrtf(invr.y);
            ivs = invr * sv;                 // invr^1.5, shared by hat & gt
            accum_set2(q + 2, rho, invr, r2, ivs, Sh[kk], Ch[kk]);
            accum_set2(q + 8, rho, invr, r2, ivs, Sg[kk], Cg[kk]);
        }
    }

    float accd = 0.0f;
    #pragma unroll
    for (int kk = 0; kk < 2; ++kk) {
        {
            float reh = Sh[kk].x - 1.0f, reg = Sg[kk].x - 1.0f;
            float vh = fmaf(reh, reh, Ch[kk].x * Ch[kk].x);
            float vg = fmaf(reg, reg, Cg[kk].x * Cg[kk].x);
            float d  = vh - vg;
            accd = fmaf(d, d, accd);
        }
        {
            float reh = Sh[kk].y - 1.0f, reg = Sg[kk].y - 1.0f;
            float vh = fmaf(reh, reh, Ch[kk].y * Ch[kk].y);
            float vg = fmaf(reg, reg, Cg[kk].y * Cg[kk].y);
            float d  = vh - vg;
            accd = fmaf(d, d, accd);
        }
    }

    #pragma unroll
    for (int off = 32; off > 0; off >>= 1) accd += __shfl_down(accd, off, 64);
    if ((threadIdx.x & 63) == 0) wsum[threadIdx.x >> 6] = accd;
    __syncthreads();
    if (threadIdx.x == 0) {
        float s = (wsum[0] + wsum[1]) + (wsum[2] + wsum[3]);
        atomicAdd(acc, (double)s);
    }
}

__global__ void finalize_kernel(const double* __restrict__ acc, float* __restrict__ out) {
    // mse * N^2 / 384^2 = sum / (B*N^2) * N^2/384^2 = sum / (2*384^2)
    out[0] = (float)(acc[0] / 294912.0);
}

extern "C" void kernel_launch(void* const* d_in, const int* in_sizes, int n_in,
                              void* d_out, int out_size, void* d_ws, size_t ws_size,
                              hipStream_t stream) {
    const float* yh  = (const float*)d_in[0];   // y_hat (2,3,512,512) f32
    const float* ygt = (const float*)d_in[1];   // y     (2,5,512,512) f32
    const int*   xs  = (const int*)d_in[2];     // (2,4) i32
    const int*   ys  = (const int*)d_in[3];     // (2,4) i32

    double* acc = (double*)d_ws;
    float*  prm = (float*)((char*)d_ws + 16);
    float*  out = (float*)d_out;

    gather_params_kernel<<<1, 128, 0, stream>>>(yh, ygt, xs, ys, prm, acc);
    holo_mse_kernel<<<8192, 256, 0, stream>>>(prm, acc);
    finalize_kernel<<<1, 1, 0, stream>>>(acc, out);
}

// Round 6
// 97.905 us; speedup vs baseline: 5.1755x; 5.1755x over previous
//
#include <hip/hip_runtime.h>
#include <math.h>

#ifndef M_PI
#define M_PI 3.14159265358979323846
#endif

// Problem constants (from the reference)
constexpr int    NSAMP  = 2048;
constexpr float  STEPf  = 2048.0f / 2047.0f;       // linspace(-1024,1024,2048) step
constexpr float  DXf    = 6.0e-6f;                 // 3e-6 / 0.5
constexpr float  EPSf   = 2.2204e-16f;
constexpr double Kd     = 2.0 * M_PI / 3.55e-7;    // ~1.7698956e7
constexpr double INV2PI = 1.0 / (2.0 * M_PI);

// ---------------------------------------------------------------------------
// Gather per-(batch,particle) parameters; precompute per-set constants (fp64).
// prm layout per (b,p), stride 16:
//   0:xm 1:ym
//   per set s in {hat,gt} at offset 2+6s:
//     +0: carg   (x = carg*rho; branch predicate)
//     +1: crev   = carg/2pi
//     +2: c8     = 8/carg                       (z = min(c8*invr, 1))
//     +3: csql   = (rs/2)*sqrt(0.636619772/carg)  (amp_l = csql*invr^1.5*B)
//     +4: camp   = rs/2                          (amp_s = camp*invr*j1s)
//     +5: cph    = K/(2*zs*2pi)
// ---------------------------------------------------------------------------
__global__ void gather_params_kernel(const float* __restrict__ yh,
                                     const float* __restrict__ ygt,
                                     const int*   __restrict__ xs,
                                     const int*   __restrict__ ys,
                                     float* __restrict__ prm,
                                     double* __restrict__ acc) {
    int t = threadIdx.x;
    if (t == 0) *acc = 0.0;   // zero accumulator every launch (graph replay safe)
    if (t < 8) {
        const int M = 512;
        int b = t >> 2, p = t & 3;
        int ix = xs[b * 4 + p];
        int iy = ys[b * 4 + p];
        float rs_h = 50.0f  * yh [((b * 3 + 2) * M + iy) * M + ix];
        float zs_h = 200.0f * yh [((b * 3 + 1) * M + iy) * M + ix];
        float rs_g =          ygt[((b * 5 + 2) * M + iy) * M + ix];
        float zs_g =          ygt[((b * 5 + 1) * M + iy) * M + ix];
        double rph = (double)rs_h * 1e-6, zph = (double)zs_h * 1e-3;
        double rpg = (double)rs_g * 1e-6, zpg = (double)zs_g * 1e-3;

        float* o = prm + t * 16;
        o[0] = ((float)(ix * 4) - 1024.0f) * DXf;
        o[1] = ((float)(iy * 4) - 1024.0f) * DXf;

        double carg_h = Kd * rph / zph;
        o[2] = (float)carg_h;
        o[3] = (float)(carg_h * INV2PI);
        o[4] = (float)(8.0 / carg_h);
        o[5] = (float)(0.5 * rph * sqrt(0.636619772 / carg_h));
        o[6] = (float)(0.5 * rph);
        o[7] = (float)(Kd / (2.0 * zph) * INV2PI);

        double carg_g = Kd * rpg / zpg;
        o[8]  = (float)carg_g;
        o[9]  = (float)(carg_g * INV2PI);
        o[10] = (float)(8.0 / carg_g);
        o[11] = (float)(0.5 * rpg * sqrt(0.636619772 / carg_g));
        o[12] = (float)(0.5 * rpg);
        o[13] = (float)(Kd / (2.0 * zpg) * INV2PI);
        o[14] = 0.0f; o[15] = 0.0f;
    }
}

// One particle-set J1*trig contribution. Scalar, branchless, all-finite on all
// lanes (both branch inputs clamped — round-2-proven codegen and numerics).
__device__ __forceinline__ void accum_set(float carg, float crev, float c8,
                                          float csql, float camp, float cph,
                                          float rho, float invr, float r2,
                                          float ivs /* invr^1.5, shared */,
                                          float& S, float& C) {
    float x = carg * rho;
    // --- small branch: NR rational on clamped xc = min(x,8) ---
    float xc  = fminf(x, 8.0f);
    float yy  = xc * xc;
    float num = xc * fmaf(yy, fmaf(yy, fmaf(yy, fmaf(yy, fmaf(yy,
                    -30.16036606f, 15704.48260f), -2972611.439f),
                    242396853.1f), -7895059235.0f), 72362614232.0f);
    float den = fmaf(yy, fmaf(yy, fmaf(yy, fmaf(yy, (yy + 376.9991397f),
                    99447.43394f), 18583304.74f), 2300535178.0f), 144725228442.0f);
    float a_s = (camp * invr) * (num * __builtin_amdgcn_rcpf(den));
    // --- large branch: asymptotic, p1/p2 truncated to 2 terms (<=4.4e-5 rel
    //     at x=8, decays as z^4); z clamped so unselected lanes stay finite ---
    float z    = fminf(c8 * invr, 1.0f);
    float y2   = z * z;
    float rev1 = fmaf(crev, rho, -0.375f);        // (x - 3pi/4)/2pi
    float f1   = __builtin_amdgcn_fractf(rev1);
    float s1   = __builtin_amdgcn_sinf(f1);
    float c1   = __builtin_amdgcn_cosf(f1);
    float p1   = fmaf(y2, 0.183105e-2f, 1.0f);
    float p2   = fmaf(y2, -0.2002690873e-3f, 0.04687499995f);
    float B    = fmaf(c1, p1, -(z * s1) * p2);
    float a_l  = (csql * ivs) * B;
    // --- select on x<8 ---
    float amp = (x < 8.0f) ? a_s : a_l;
    // --- phase: rev = cph*r2, FMA residual restores low bits ---
    float hi  = cph * r2;
    float err = fmaf(cph, r2, -hi);
    float fr  = __builtin_amdgcn_fractf(hi) + err;
    float s2  = __builtin_amdgcn_sinf(fr);
    float c2  = __builtin_amdgcn_cosf(fr);
    S = fmaf(amp, s2, S);
    C = fmaf(amp, c2, C);
}

// 4096 blocks x 256 threads; each thread does 8 points (same j, rows i0+256k),
// block-uniform batch index.
__global__ __launch_bounds__(256, 4) void holo_mse_kernel(
        const float* __restrict__ prm, double* __restrict__ acc) {
    __shared__ float sp[128];
    __shared__ float wsum[4];
    if (threadIdx.x < 128) sp[threadIdx.x] = prm[threadIdx.x];
    __syncthreads();

    int blk = blockIdx.x;
    int b   = blk >> 11;                            // block-uniform batch
    int r   = ((blk & 2047) << 8) + threadIdx.x;    // [0, 524288)
    int i0  = r >> 11;                              // row base (0..255)
    int j   = r & (NSAMP - 1);

    float nj = fmaf((float)j, STEPf, -1024.0f) * DXf;
    float ni[8];
    #pragma unroll
    for (int k = 0; k < 8; ++k)
        ni[k] = fmaf((float)(i0 + 256 * k), STEPf, -1024.0f) * DXf;

    float Sh[8], Ch[8], Sg[8], Cg[8];
    #pragma unroll
    for (int k = 0; k < 8; ++k) { Sh[k] = Ch[k] = Sg[k] = Cg[k] = 0.0f; }

    #pragma unroll
    for (int p = 0; p < 4; ++p) {
        const float* q = &sp[(b * 4 + p) * 16];
        float xm = q[0], ym = q[1];
        float carg_h = q[2], crev_h = q[3], c8_h = q[4],
              csql_h = q[5], camp_h = q[6], cph_h = q[7];
        float carg_g = q[8], crev_g = q[9], c8_g = q[10],
              csql_g = q[11], camp_g = q[12], cph_g = q[13];
        float dx  = (nj - xm) + EPSf;
        float dx2 = dx * dx;
        #pragma unroll
        for (int k = 0; k < 8; ++k) {
            float dy   = (ni[k] - ym) + EPSf;
            float r2   = fmaf(dy, dy, dx2);
            float invr = __builtin_amdgcn_rsqf(r2);
            float rho  = r2 * invr;
            float ivs  = invr * __builtin_amdgcn_sqrtf(invr);  // invr^1.5, shared
            accum_set(carg_h, crev_h, c8_h, csql_h, camp_h, cph_h,
                      rho, invr, r2, ivs, Sh[k], Ch[k]);
            accum_set(carg_g, crev_g, c8_g, csql_g, camp_g, cph_g,
                      rho, invr, r2, ivs, Sg[k], Cg[k]);
        }
    }

    float accd = 0.0f;
    #pragma unroll
    for (int k = 0; k < 8; ++k) {
        float reh = Sh[k] - 1.0f, reg = Sg[k] - 1.0f;
        float vh  = fmaf(reh, reh, Ch[k] * Ch[k]);
        float vg  = fmaf(reg, reg, Cg[k] * Cg[k]);
        float d   = vh - vg;
        accd = fmaf(d, d, accd);
    }

    #pragma unroll
    for (int off = 32; off > 0; off >>= 1) accd += __shfl_down(accd, off, 64);
    if ((threadIdx.x & 63) == 0) wsum[threadIdx.x >> 6] = accd;
    __syncthreads();
    if (threadIdx.x == 0) {
        float s = (wsum[0] + wsum[1]) + (wsum[2] + wsum[3]);
        atomicAdd(acc, (double)s);
    }
}

__global__ void finalize_kernel(const double* __restrict__ acc, float* __restrict__ out) {
    // mse * N^2 / 384^2 = sum / (B*N^2) * N^2/384^2 = sum / (2*384^2)
    out[0] = (float)(acc[0] / 294912.0);
}

extern "C" void kernel_launch(void* const* d_in, const int* in_sizes, int n_in,
                              void* d_out, int out_size, void* d_ws, size_t ws_size,
                              hipStream_t stream) {
    const float* yh  = (const float*)d_in[0];   // y_hat (2,3,512,512) f32
    const float* ygt = (const float*)d_in[1];   // y     (2,5,512,512) f32
    const int*   xs  = (const int*)d_in[2];     // (2,4) i32
    const int*   ys  = (const int*)d_in[3];     // (2,4) i32

    double* acc = (double*)d_ws;
    float*  prm = (float*)((char*)d_ws + 16);
    float*  out = (float*)d_out;

    gather_params_kernel<<<1, 128, 0, stream>>>(yh, ygt, xs, ys, prm, acc);
    holo_mse_kernel<<<4096, 256, 0, stream>>>(prm, acc);
    finalize_kernel<<<1, 1, 0, stream>>>(acc, out);
}